// Round 2
// baseline (1292.915 us; speedup 1.0000x reference)
//
#include <hip/hip_runtime.h>

#define N_NODES 50000
#define N_EDGES 800000
#define IN_DIM  1024
#define COUT    127
#define KPAD1   128
#define H1      256
#define H2      128
#define MBLK    391          // ceil(50000/128)

// ---------------- conv1d: h[N,1024] -> x1[N,128] (col 127 = 0 pad) ----------
__global__ void conv_kernel(const float* __restrict__ h, const float* __restrict__ w,
                            const float* __restrict__ b, float* __restrict__ x1) {
    int n = blockIdx.x;
    int t = threadIdx.x;
    const float* hr = h + (size_t)n * IN_DIM;
    if (t < COUT) {
        const float* p = hr + t * 8;              // 32B aligned
        float4 a = *(const float4*)p;
        float4 c = *(const float4*)(p + 4);
        float2 d = *(const float2*)(p + 8);
        float s = b[0];
        s += a.x * w[0] + a.y * w[1] + a.z * w[2] + a.w * w[3];
        s += c.x * w[4] + c.y * w[5] + c.z * w[6] + c.w * w[7];
        s += d.x * w[8] + d.y * w[9];
        x1[(size_t)n * KPAD1 + t] = fmaxf(s, 0.f);
    } else {
        x1[(size_t)n * KPAD1 + t] = 0.f;          // zero pad column 127
    }
}

// ---------------- CSR build ----------------
__global__ void deg_kernel(const int* __restrict__ dst, int* __restrict__ deg) {
    int e = blockIdx.x * blockDim.x + threadIdx.x;
    if (e < N_EDGES) atomicAdd(&deg[dst[e]], 1);
}

__global__ __launch_bounds__(1024) void scan_kernel(const int* __restrict__ deg,
                                                    int* __restrict__ rowptr,
                                                    int* __restrict__ cursor) {
    __shared__ int wsum[16];
    __shared__ int carry_s;
    int tid = threadIdx.x;
    int lane = tid & 63, wid = tid >> 6;
    if (tid == 0) carry_s = 0;
    __syncthreads();
    for (int base = 0; base < N_NODES; base += 1024) {
        int i = base + tid;
        int v = (i < N_NODES) ? deg[i] : 0;
        int s = v;
        #pragma unroll
        for (int off = 1; off < 64; off <<= 1) {
            int t = __shfl_up(s, off);
            if (lane >= off) s += t;
        }
        if (lane == 63) wsum[wid] = s;
        __syncthreads();
        if (tid < 16) {
            int ws = wsum[tid];
            #pragma unroll
            for (int off = 1; off < 16; off <<= 1) {
                int t = __shfl_up(ws, off);
                if (tid >= off) ws += t;
            }
            wsum[tid] = ws;
        }
        __syncthreads();
        int wpre = (wid == 0) ? 0 : wsum[wid - 1];
        int excl = carry_s + wpre + (s - v);
        if (i < N_NODES) { rowptr[i] = excl; cursor[i] = excl; }
        int tot = wsum[15];
        __syncthreads();
        if (tid == 0) carry_s += tot;
        __syncthreads();
    }
    if (tid == 0) rowptr[N_NODES] = carry_s;
}

__global__ void fill_kernel(const int* __restrict__ src, const int* __restrict__ dst,
                            int* __restrict__ cursor, int* __restrict__ esrc) {
    int e = blockIdx.x * blockDim.x + threadIdx.x;
    if (e < N_EDGES) {
        int d = dst[e];
        int pos = atomicAdd(&cursor[d], 1);
        esrc[pos] = src[e];
    }
}

// ---------------- mean aggregation (gather over CSR), 4-deep ILP ------------
template <int LDX>
__global__ void agg_kernel(const float* __restrict__ X, const int* __restrict__ rowptr,
                           const int* __restrict__ esrc, float* __restrict__ out) {
    int n = blockIdx.x;
    int f = threadIdx.x;                           // blockDim.x == LDX
    int s0 = rowptr[n], s1 = rowptr[n + 1];
    float acc = 0.f;
    int e = s0;
    for (; e + 4 <= s1; e += 4) {
        int i0 = esrc[e], i1 = esrc[e + 1], i2 = esrc[e + 2], i3 = esrc[e + 3];
        float v0 = X[(size_t)i0 * LDX + f];
        float v1 = X[(size_t)i1 * LDX + f];
        float v2 = X[(size_t)i2 * LDX + f];
        float v3 = X[(size_t)i3 * LDX + f];
        acc += (v0 + v1) + (v2 + v3);
    }
    for (; e < s1; ++e) acc += X[(size_t)esrc[e] * LDX + f];
    float dnm = (float)max(s1 - s0, 1);
    out[(size_t)n * LDX + f] = acc / dnm;
}

// ---------------- pad SAGE1 weights 127x256 -> 128x256 (row 127 = 0) --------
__global__ void padw_kernel(const float* __restrict__ ws, const float* __restrict__ wn,
                            float* __restrict__ wsp, float* __restrict__ wnp) {
    int i = blockIdx.x * blockDim.x + threadIdx.x; // 0 .. 128*256-1
    int row = i >> 8;
    float vs = 0.f, vn = 0.f;
    if (row < COUT) { vs = ws[i]; vn = wn[i]; }
    wsp[i] = vs;
    wnp[i] = vn;
}

// ---------------- SAGE1 GEMM: out = relu(X@Ws + A@Wn + b) -------------------
// X,A: [N,128]; Ws,Wn: [128,256]; out: [N,256]. 128x128 tile, 8x8/thread.
__global__ __launch_bounds__(256) void sage1_gemm(
        const float* __restrict__ X, const float* __restrict__ A,
        const float* __restrict__ Ws, const float* __restrict__ Wn,
        const float* __restrict__ bias, float* __restrict__ out) {
    __shared__ float AsX[16][132], AsA[16][132], BsS[16][132], BsN[16][132];
    int tid = threadIdx.x;
    int tx = tid & 15, ty = tid >> 4;
    int m0 = blockIdx.x * 128;
    int j0 = blockIdx.y * 128;
    float acc[8][8] = {};
    int ar = tid >> 1, ak = (tid & 1) * 8;         // A staging: 128 rows x 16 k
    int br = tid >> 4, bc = (tid & 15) * 8;        // B staging: 16 k x 128 cols

    for (int k0 = 0; k0 < KPAD1; k0 += 16) {
        float4 xv0, xv1, av0, av1;
        int gr = m0 + ar;
        if (gr < N_NODES) {
            const float* xp = X + (size_t)gr * KPAD1 + k0 + ak;
            const float* ap = A + (size_t)gr * KPAD1 + k0 + ak;
            xv0 = *(const float4*)xp;  xv1 = *(const float4*)(xp + 4);
            av0 = *(const float4*)ap;  av1 = *(const float4*)(ap + 4);
        } else {
            xv0 = xv1 = av0 = av1 = make_float4(0.f, 0.f, 0.f, 0.f);
        }
        const float* bsp = Ws + (size_t)(k0 + br) * H1 + j0 + bc;
        const float* bnp = Wn + (size_t)(k0 + br) * H1 + j0 + bc;
        float4 bs0 = *(const float4*)bsp;  float4 bs1 = *(const float4*)(bsp + 4);
        float4 bn0 = *(const float4*)bnp;  float4 bn1 = *(const float4*)(bnp + 4);

        __syncthreads();
        AsX[ak + 0][ar] = xv0.x;  AsX[ak + 1][ar] = xv0.y;
        AsX[ak + 2][ar] = xv0.z;  AsX[ak + 3][ar] = xv0.w;
        AsX[ak + 4][ar] = xv1.x;  AsX[ak + 5][ar] = xv1.y;
        AsX[ak + 6][ar] = xv1.z;  AsX[ak + 7][ar] = xv1.w;
        AsA[ak + 0][ar] = av0.x;  AsA[ak + 1][ar] = av0.y;
        AsA[ak + 2][ar] = av0.z;  AsA[ak + 3][ar] = av0.w;
        AsA[ak + 4][ar] = av1.x;  AsA[ak + 5][ar] = av1.y;
        AsA[ak + 6][ar] = av1.z;  AsA[ak + 7][ar] = av1.w;
        *(float4*)&BsS[br][bc]     = bs0;  *(float4*)&BsS[br][bc + 4] = bs1;
        *(float4*)&BsN[br][bc]     = bn0;  *(float4*)&BsN[br][bc + 4] = bn1;
        __syncthreads();

        #pragma unroll
        for (int kk = 0; kk < 16; ++kk) {
            float4 x0 = *(float4*)&AsX[kk][ty * 4];
            float4 x1 = *(float4*)&AsX[kk][64 + ty * 4];
            float4 a0 = *(float4*)&AsA[kk][ty * 4];
            float4 a1 = *(float4*)&AsA[kk][64 + ty * 4];
            float4 s0 = *(float4*)&BsS[kk][tx * 4];
            float4 s1 = *(float4*)&BsS[kk][64 + tx * 4];
            float4 n0 = *(float4*)&BsN[kk][tx * 4];
            float4 n1 = *(float4*)&BsN[kk][64 + tx * 4];
            float xr[8] = {x0.x, x0.y, x0.z, x0.w, x1.x, x1.y, x1.z, x1.w};
            float ar8[8] = {a0.x, a0.y, a0.z, a0.w, a1.x, a1.y, a1.z, a1.w};
            float sr[8] = {s0.x, s0.y, s0.z, s0.w, s1.x, s1.y, s1.z, s1.w};
            float nr[8] = {n0.x, n0.y, n0.z, n0.w, n1.x, n1.y, n1.z, n1.w};
            #pragma unroll
            for (int i = 0; i < 8; ++i)
                #pragma unroll
                for (int j = 0; j < 8; ++j)
                    acc[i][j] += xr[i] * sr[j] + ar8[i] * nr[j];
        }
    }

    float4 bv0 = *(const float4*)&bias[j0 + tx * 4];
    float4 bv1 = *(const float4*)&bias[j0 + 64 + tx * 4];
    float bb[8] = {bv0.x, bv0.y, bv0.z, bv0.w, bv1.x, bv1.y, bv1.z, bv1.w};
    #pragma unroll
    for (int g = 0; g < 2; ++g) {
        #pragma unroll
        for (int r = 0; r < 4; ++r) {
            int m = m0 + g * 64 + ty * 4 + r;
            if (m < N_NODES) {
                int i = g * 4 + r;
                float4 o0, o1;
                o0.x = fmaxf(acc[i][0] + bb[0], 0.f);
                o0.y = fmaxf(acc[i][1] + bb[1], 0.f);
                o0.z = fmaxf(acc[i][2] + bb[2], 0.f);
                o0.w = fmaxf(acc[i][3] + bb[3], 0.f);
                o1.x = fmaxf(acc[i][4] + bb[4], 0.f);
                o1.y = fmaxf(acc[i][5] + bb[5], 0.f);
                o1.z = fmaxf(acc[i][6] + bb[6], 0.f);
                o1.w = fmaxf(acc[i][7] + bb[7], 0.f);
                *(float4*)&out[(size_t)m * H1 + j0 + tx * 4]      = o0;
                *(float4*)&out[(size_t)m * H1 + j0 + 64 + tx * 4] = o1;
            }
        }
    }
}

// ---------------- layer-2 projection: P[:,j0:j0+128] = x2 @ W ---------------
// x2: [N,256]; W (Ws2 if blockIdx.y==0 else Wn2): [256,128]; P: [N,256].
// No bias/relu here (applied in agg_epi). 128x128 tile, 8x8/thread, K=256.
__global__ __launch_bounds__(256) void proj2_gemm(
        const float* __restrict__ X, const float* __restrict__ Ws2,
        const float* __restrict__ Wn2, float* __restrict__ P) {
    __shared__ float As[16][132], Bs[16][132];
    int tid = threadIdx.x;
    int tx = tid & 15, ty = tid >> 4;
    int m0 = blockIdx.x * 128;
    int j0 = blockIdx.y * 128;
    const float* W = (blockIdx.y == 0) ? Ws2 : Wn2;
    float acc[8][8] = {};
    int ar = tid >> 1, ak = (tid & 1) * 8;
    int br = tid >> 4, bc = (tid & 15) * 8;

    for (int k0 = 0; k0 < H1; k0 += 16) {
        float4 xv0, xv1;
        int gr = m0 + ar;
        if (gr < N_NODES) {
            const float* xp = X + (size_t)gr * H1 + k0 + ak;
            xv0 = *(const float4*)xp;  xv1 = *(const float4*)(xp + 4);
        } else {
            xv0 = xv1 = make_float4(0.f, 0.f, 0.f, 0.f);
        }
        const float* bp = W + (size_t)(k0 + br) * H2 + bc;
        float4 b0 = *(const float4*)bp;  float4 b1 = *(const float4*)(bp + 4);

        __syncthreads();
        As[ak + 0][ar] = xv0.x;  As[ak + 1][ar] = xv0.y;
        As[ak + 2][ar] = xv0.z;  As[ak + 3][ar] = xv0.w;
        As[ak + 4][ar] = xv1.x;  As[ak + 5][ar] = xv1.y;
        As[ak + 6][ar] = xv1.z;  As[ak + 7][ar] = xv1.w;
        *(float4*)&Bs[br][bc]     = b0;  *(float4*)&Bs[br][bc + 4] = b1;
        __syncthreads();

        #pragma unroll
        for (int kk = 0; kk < 16; ++kk) {
            float4 a0 = *(float4*)&As[kk][ty * 4];
            float4 a1 = *(float4*)&As[kk][64 + ty * 4];
            float4 b0f = *(float4*)&Bs[kk][tx * 4];
            float4 b1f = *(float4*)&Bs[kk][64 + tx * 4];
            float ax[8] = {a0.x, a0.y, a0.z, a0.w, a1.x, a1.y, a1.z, a1.w};
            float bx[8] = {b0f.x, b0f.y, b0f.z, b0f.w, b1f.x, b1f.y, b1f.z, b1f.w};
            #pragma unroll
            for (int i = 0; i < 8; ++i)
                #pragma unroll
                for (int j = 0; j < 8; ++j)
                    acc[i][j] += ax[i] * bx[j];
        }
    }

    #pragma unroll
    for (int g = 0; g < 2; ++g) {
        #pragma unroll
        for (int r = 0; r < 4; ++r) {
            int m = m0 + g * 64 + ty * 4 + r;
            if (m < N_NODES) {
                int i = g * 4 + r;
                float4 o0 = make_float4(acc[i][0], acc[i][1], acc[i][2], acc[i][3]);
                float4 o1 = make_float4(acc[i][4], acc[i][5], acc[i][6], acc[i][7]);
                *(float4*)&P[(size_t)m * H1 + j0 + tx * 4]      = o0;
                *(float4*)&P[(size_t)m * H1 + j0 + 64 + tx * 4] = o1;
            }
        }
    }
}

// ---------------- layer-2 aggregate + epilogue + pool -----------------------
// P[:, :128] = x2@Ws2 (self), P[:, 128:] = x2@Wn2 (neigh projection).
// y2[n] = relu(P[n,:128] + mean_{src in N(n)} P[src,128:] + b2); hg += y2.
__global__ __launch_bounds__(128) void agg_epi_kernel(
        const float* __restrict__ P, const int* __restrict__ rowptr,
        const int* __restrict__ esrc, const float* __restrict__ b2,
        float* __restrict__ hg) {
    int f = threadIdx.x;
    float bf = b2[f];
    float csum = 0.f;
    for (int n = blockIdx.x; n < N_NODES; n += gridDim.x) {
        int s0 = rowptr[n], s1 = rowptr[n + 1];
        float acc = 0.f;
        int e = s0;
        for (; e + 4 <= s1; e += 4) {
            int i0 = esrc[e], i1 = esrc[e + 1], i2 = esrc[e + 2], i3 = esrc[e + 3];
            float v0 = P[(size_t)i0 * H1 + H2 + f];
            float v1 = P[(size_t)i1 * H1 + H2 + f];
            float v2 = P[(size_t)i2 * H1 + H2 + f];
            float v3 = P[(size_t)i3 * H1 + H2 + f];
            acc += (v0 + v1) + (v2 + v3);
        }
        for (; e < s1; ++e) acc += P[(size_t)esrc[e] * H1 + H2 + f];
        float dnm = (float)max(s1 - s0, 1);
        float y = P[(size_t)n * H1 + f] + acc / dnm + bf;
        csum += fmaxf(y, 0.f);
    }
    atomicAdd(&hg[f], csum);
}

// ---------------- mean + MLP head (single block) ----------------
__global__ void mlp_kernel(const float* __restrict__ hg,
                           const float* __restrict__ f1w, const float* __restrict__ f1b,
                           const float* __restrict__ f2w, const float* __restrict__ f2b,
                           const float* __restrict__ f3w, const float* __restrict__ f3b,
                           float* __restrict__ out) {
    __shared__ float h0[128], y1[64], y2[32];
    int t = threadIdx.x;
    if (t < 128) h0[t] = hg[t] * (1.0f / N_NODES);
    __syncthreads();
    if (t < 64) {
        float s = f1b[t];
        for (int k = 0; k < 128; ++k) s += h0[k] * f1w[k * 64 + t];
        y1[t] = fmaxf(s, 0.f);
    }
    __syncthreads();
    if (t < 32) {
        float s = f2b[t];
        for (int k = 0; k < 64; ++k) s += y1[k] * f2w[k * 32 + t];
        y2[t] = fmaxf(s, 0.f);
    }
    __syncthreads();
    if (t == 0) {
        float s = f3b[0];
        for (int k = 0; k < 32; ++k) s += y2[k] * f3w[k];
        out[0] = s;
    }
}

extern "C" void kernel_launch(void* const* d_in, const int* in_sizes, int n_in,
                              void* d_out, int out_size, void* d_ws, size_t ws_size,
                              hipStream_t stream) {
    (void)in_sizes; (void)n_in; (void)out_size; (void)ws_size;
    const float* h        = (const float*)d_in[0];
    const int*   src      = (const int*)d_in[1];
    const int*   dst      = (const int*)d_in[2];
    const float* cw       = (const float*)d_in[3];
    const float* cb       = (const float*)d_in[4];
    const float* w_self1  = (const float*)d_in[5];
    const float* w_neigh1 = (const float*)d_in[6];
    const float* b1       = (const float*)d_in[7];
    const float* w_self2  = (const float*)d_in[8];
    const float* w_neigh2 = (const float*)d_in[9];
    const float* b2       = (const float*)d_in[10];
    const float* f1w      = (const float*)d_in[11];
    const float* f1b      = (const float*)d_in[12];
    const float* f2w      = (const float*)d_in[13];
    const float* f2b      = (const float*)d_in[14];
    const float* f3w      = (const float*)d_in[15];
    const float* f3b      = (const float*)d_in[16];
    float* out = (float*)d_out;

    // workspace layout (bytes); P overlays x1+agg1 (both dead after sage1_gemm)
    char* ws = (char*)d_ws;
    float* x1    = (float*)(ws + 0);           // 50048*128*4 = 25,624,576
    float* agg1  = (float*)(ws + 25624576);    // 25,624,576
    float* P     = (float*)(ws + 0);           // 50048*256*4 = 51,249,152 (overlay)
    float* x2    = (float*)(ws + 51249152);    // 51,249,152
    float* wsp1  = (float*)(ws + 102498304);   // 131,072
    float* wnp1  = (float*)(ws + 102629376);   // 131,072
    int*   deg   = (int*)  (ws + 102760448);   // 200,192
    int*   rowp  = (int*)  (ws + 102960640);   // 200,448
    int*   cur   = (int*)  (ws + 103161088);   // 200,192
    int*   esrc  = (int*)  (ws + 103361280);   // 3,200,000
    float* hg    = (float*)(ws + 106561280);   // 512    (total ~106.6 MB)

    hipMemsetAsync(deg, 0, N_NODES * sizeof(int), stream);
    hipMemsetAsync(hg, 0, 128 * sizeof(float), stream);

    padw_kernel<<<128, 256, 0, stream>>>(w_self1, w_neigh1, wsp1, wnp1);
    deg_kernel<<<(N_EDGES + 255) / 256, 256, 0, stream>>>(dst, deg);
    scan_kernel<<<1, 1024, 0, stream>>>(deg, rowp, cur);
    fill_kernel<<<(N_EDGES + 255) / 256, 256, 0, stream>>>(src, dst, cur, esrc);
    conv_kernel<<<N_NODES, 128, 0, stream>>>(h, cw, cb, x1);
    agg_kernel<128><<<N_NODES, 128, 0, stream>>>(x1, rowp, esrc, agg1);
    dim3 g1(MBLK, 2);
    sage1_gemm<<<g1, 256, 0, stream>>>(x1, agg1, wsp1, wnp1, b1, x2);
    dim3 g2(MBLK, 2);
    proj2_gemm<<<g2, 256, 0, stream>>>(x2, w_self2, w_neigh2, P);
    agg_epi_kernel<<<512, 128, 0, stream>>>(P, rowp, esrc, b2, hg);
    mlp_kernel<<<1, 128, 0, stream>>>(hg, f1w, f1b, f2w, f2b, f3w, f3b, out);
}

// Round 3
// 992.798 us; speedup vs baseline: 1.3023x; 1.3023x over previous
//
#include <hip/hip_runtime.h>

#define N_NODES 50000
#define N_EDGES 800000
#define IN_DIM  1024
#define COUT    127
#define H1      256
#define H2      128
#define LDA     256          // row stride of xa / x2 / P
#define MBLK    391          // ceil(50000/128)

// ---- conv1d: h[N,1024] -> xa[:, 0:128] (col 127 = 0 pad), row stride 256 ---
__global__ void conv_kernel(const float* __restrict__ h, const float* __restrict__ w,
                            const float* __restrict__ b, float* __restrict__ xa) {
    int n = blockIdx.x;
    int t = threadIdx.x;                           // 0..127
    const float* hr = h + (size_t)n * IN_DIM;
    float r = 0.f;
    if (t < COUT) {
        const float* p = hr + t * 8;               // 32B aligned
        float4 a = *(const float4*)p;
        float4 c = *(const float4*)(p + 4);
        float2 d = *(const float2*)(p + 8);
        float s = b[0];
        s += a.x * w[0] + a.y * w[1] + a.z * w[2] + a.w * w[3];
        s += c.x * w[4] + c.y * w[5] + c.z * w[6] + c.w * w[7];
        s += d.x * w[8] + d.y * w[9];
        r = fmaxf(s, 0.f);
    }
    xa[(size_t)n * LDA + t] = r;
}

// ---------------- CSR build ----------------
__global__ void deg_kernel(const int* __restrict__ dst, int* __restrict__ deg) {
    int e = blockIdx.x * blockDim.x + threadIdx.x;
    if (e < N_EDGES) atomicAdd(&deg[dst[e]], 1);
}

// cursor may alias deg (deg[i] is read before cursor[i] is written, same thread)
__global__ __launch_bounds__(1024) void scan_kernel(const int* __restrict__ deg,
                                                    int* __restrict__ rowptr,
                                                    int* __restrict__ cursor) {
    __shared__ int wsum[16];
    __shared__ int carry_s;
    int tid = threadIdx.x;
    int lane = tid & 63, wid = tid >> 6;
    if (tid == 0) carry_s = 0;
    __syncthreads();
    for (int base = 0; base < N_NODES; base += 1024) {
        int i = base + tid;
        int v = (i < N_NODES) ? deg[i] : 0;
        int s = v;
        #pragma unroll
        for (int off = 1; off < 64; off <<= 1) {
            int t = __shfl_up(s, off);
            if (lane >= off) s += t;
        }
        if (lane == 63) wsum[wid] = s;
        __syncthreads();
        if (tid < 16) {
            int ws = wsum[tid];
            #pragma unroll
            for (int off = 1; off < 16; off <<= 1) {
                int t = __shfl_up(ws, off);
                if (tid >= off) ws += t;
            }
            wsum[tid] = ws;
        }
        __syncthreads();
        int wpre = (wid == 0) ? 0 : wsum[wid - 1];
        int excl = carry_s + wpre + (s - v);
        if (i < N_NODES) { rowptr[i] = excl; cursor[i] = excl; }
        int tot = wsum[15];
        __syncthreads();
        if (tid == 0) carry_s += tot;
        __syncthreads();
    }
    if (tid == 0) rowptr[N_NODES] = carry_s;
}

__global__ void fill_kernel(const int* __restrict__ src, const int* __restrict__ dst,
                            int* __restrict__ cursor, int* __restrict__ esrc) {
    int e = blockIdx.x * blockDim.x + threadIdx.x;
    if (e < N_EDGES) {
        int d = dst[e];
        int pos = atomicAdd(&cursor[d], 1);
        esrc[pos] = src[e];
    }
}

// ---- mean aggregation: xa[:, 128:256] = mean of in-neighbor xa[:, 0:128] ---
__global__ void agg_kernel(float* __restrict__ xa, const int* __restrict__ rowptr,
                           const int* __restrict__ esrc) {
    int n = blockIdx.x;
    int f = threadIdx.x;                           // 0..127
    int s0 = rowptr[n], s1 = rowptr[n + 1];
    float acc = 0.f;
    int e = s0;
    for (; e + 4 <= s1; e += 4) {
        int i0 = esrc[e], i1 = esrc[e + 1], i2 = esrc[e + 2], i3 = esrc[e + 3];
        float v0 = xa[(size_t)i0 * LDA + f];
        float v1 = xa[(size_t)i1 * LDA + f];
        float v2 = xa[(size_t)i2 * LDA + f];
        float v3 = xa[(size_t)i3 * LDA + f];
        acc += (v0 + v1) + (v2 + v3);
    }
    for (; e < s1; ++e) acc += xa[(size_t)esrc[e] * LDA + f];
    float dnm = (float)max(s1 - s0, 1);
    xa[(size_t)n * LDA + 128 + f] = acc / dnm;
}

// ---- Wcat1[256][256]: rows 0..126 = Ws1, row 127 = 0, 128..254 = Wn1, 255 = 0
__global__ void padw1_kernel(const float* __restrict__ ws, const float* __restrict__ wn,
                             float* __restrict__ wcat) {
    int i = blockIdx.x * blockDim.x + threadIdx.x; // 0 .. 256*256-1
    int row = i >> 8, col = i & 255;
    float v = 0.f;
    if (row < COUT)                 v = ws[row * H1 + col];
    else if (row >= 128 && row < 128 + COUT) v = wn[(row - 128) * H1 + col];
    wcat[i] = v;
}

// ---- Wcat2[256][256]: cols 0..127 = Ws2, cols 128..255 = Wn2 ----------------
__global__ void padw2_kernel(const float* __restrict__ ws, const float* __restrict__ wn,
                             float* __restrict__ wcat) {
    int i = blockIdx.x * blockDim.x + threadIdx.x; // 0 .. 256*256-1
    int row = i >> 8, col = i & 255;
    wcat[i] = (col < H2) ? ws[row * H2 + col] : wn[row * H2 + (col - H2)];
}

// ---- generic GEMM: out[N,256] = (relu?)(X[N,256] @ W[256,256] (+ bias)) ----
// 128x128 tile, 8x8 per thread, K=256.
template <bool RELU>
__global__ __launch_bounds__(256) void gemm256(
        const float* __restrict__ X, const float* __restrict__ W,
        const float* __restrict__ bias, float* __restrict__ out) {
    __shared__ float As[16][132], Bs[16][132];
    int tid = threadIdx.x;
    int tx = tid & 15, ty = tid >> 4;
    int m0 = blockIdx.x * 128;
    int j0 = blockIdx.y * 128;
    float acc[8][8] = {};
    int ar = tid >> 1, ak = (tid & 1) * 8;         // A staging: 128 rows x 16 k
    int br = tid >> 4, bc = (tid & 15) * 8;        // B staging: 16 k x 128 cols

    for (int k0 = 0; k0 < 256; k0 += 16) {
        float4 xv0, xv1;
        int gr = m0 + ar;
        if (gr < N_NODES) {
            const float* xp = X + (size_t)gr * LDA + k0 + ak;
            xv0 = *(const float4*)xp;  xv1 = *(const float4*)(xp + 4);
        } else {
            xv0 = xv1 = make_float4(0.f, 0.f, 0.f, 0.f);
        }
        const float* bp = W + (size_t)(k0 + br) * 256 + j0 + bc;
        float4 b0 = *(const float4*)bp;  float4 b1 = *(const float4*)(bp + 4);

        __syncthreads();
        As[ak + 0][ar] = xv0.x;  As[ak + 1][ar] = xv0.y;
        As[ak + 2][ar] = xv0.z;  As[ak + 3][ar] = xv0.w;
        As[ak + 4][ar] = xv1.x;  As[ak + 5][ar] = xv1.y;
        As[ak + 6][ar] = xv1.z;  As[ak + 7][ar] = xv1.w;
        *(float4*)&Bs[br][bc]     = b0;  *(float4*)&Bs[br][bc + 4] = b1;
        __syncthreads();

        #pragma unroll
        for (int kk = 0; kk < 16; ++kk) {
            float4 a0 = *(float4*)&As[kk][ty * 4];
            float4 a1 = *(float4*)&As[kk][64 + ty * 4];
            float4 b0f = *(float4*)&Bs[kk][tx * 4];
            float4 b1f = *(float4*)&Bs[kk][64 + tx * 4];
            float ax[8] = {a0.x, a0.y, a0.z, a0.w, a1.x, a1.y, a1.z, a1.w};
            float bx[8] = {b0f.x, b0f.y, b0f.z, b0f.w, b1f.x, b1f.y, b1f.z, b1f.w};
            #pragma unroll
            for (int i = 0; i < 8; ++i)
                #pragma unroll
                for (int j = 0; j < 8; ++j)
                    acc[i][j] += ax[i] * bx[j];
        }
    }

    float bb[8] = {};
    if constexpr (RELU) {
        float4 bv0 = *(const float4*)&bias[j0 + tx * 4];
        float4 bv1 = *(const float4*)&bias[j0 + 64 + tx * 4];
        bb[0] = bv0.x; bb[1] = bv0.y; bb[2] = bv0.z; bb[3] = bv0.w;
        bb[4] = bv1.x; bb[5] = bv1.y; bb[6] = bv1.z; bb[7] = bv1.w;
    }
    #pragma unroll
    for (int g = 0; g < 2; ++g) {
        #pragma unroll
        for (int r = 0; r < 4; ++r) {
            int m = m0 + g * 64 + ty * 4 + r;
            if (m < N_NODES) {
                int i = g * 4 + r;
                float4 o0, o1;
                if constexpr (RELU) {
                    o0.x = fmaxf(acc[i][0] + bb[0], 0.f);
                    o0.y = fmaxf(acc[i][1] + bb[1], 0.f);
                    o0.z = fmaxf(acc[i][2] + bb[2], 0.f);
                    o0.w = fmaxf(acc[i][3] + bb[3], 0.f);
                    o1.x = fmaxf(acc[i][4] + bb[4], 0.f);
                    o1.y = fmaxf(acc[i][5] + bb[5], 0.f);
                    o1.z = fmaxf(acc[i][6] + bb[6], 0.f);
                    o1.w = fmaxf(acc[i][7] + bb[7], 0.f);
                } else {
                    o0 = make_float4(acc[i][0], acc[i][1], acc[i][2], acc[i][3]);
                    o1 = make_float4(acc[i][4], acc[i][5], acc[i][6], acc[i][7]);
                }
                *(float4*)&out[(size_t)m * LDA + j0 + tx * 4]      = o0;
                *(float4*)&out[(size_t)m * LDA + j0 + 64 + tx * 4] = o1;
            }
        }
    }
}

// ---- layer-2 aggregate + epilogue + pool ------------------------------------
// P[:, :128] = x2@Ws2 (self), P[:, 128:] = x2@Wn2 (neigh projection).
// y2[n] = relu(P[n,:128] + mean_{src in N(n)} P[src,128:] + b2); hg += sum y2.
__global__ __launch_bounds__(128) void agg_epi_kernel(
        const float* __restrict__ P, const int* __restrict__ rowptr,
        const int* __restrict__ esrc, const float* __restrict__ b2,
        float* __restrict__ hg) {
    int f = threadIdx.x;
    float bf = b2[f];
    float csum = 0.f;
    for (int n = blockIdx.x; n < N_NODES; n += gridDim.x) {
        int s0 = rowptr[n], s1 = rowptr[n + 1];
        float acc = 0.f;
        int e = s0;
        for (; e + 4 <= s1; e += 4) {
            int i0 = esrc[e], i1 = esrc[e + 1], i2 = esrc[e + 2], i3 = esrc[e + 3];
            float v0 = P[(size_t)i0 * LDA + H2 + f];
            float v1 = P[(size_t)i1 * LDA + H2 + f];
            float v2 = P[(size_t)i2 * LDA + H2 + f];
            float v3 = P[(size_t)i3 * LDA + H2 + f];
            acc += (v0 + v1) + (v2 + v3);
        }
        for (; e < s1; ++e) acc += P[(size_t)esrc[e] * LDA + H2 + f];
        float dnm = (float)max(s1 - s0, 1);
        float y = P[(size_t)n * LDA + f] + acc / dnm + bf;
        csum += fmaxf(y, 0.f);
    }
    atomicAdd(&hg[f], csum);
}

// ---------------- mean + MLP head (single block) ----------------
__global__ void mlp_kernel(const float* __restrict__ hg,
                           const float* __restrict__ f1w, const float* __restrict__ f1b,
                           const float* __restrict__ f2w, const float* __restrict__ f2b,
                           const float* __restrict__ f3w, const float* __restrict__ f3b,
                           float* __restrict__ out) {
    __shared__ float h0[128], y1[64], y2[32];
    int t = threadIdx.x;
    if (t < 128) h0[t] = hg[t] * (1.0f / N_NODES);
    __syncthreads();
    if (t < 64) {
        float s = f1b[t];
        for (int k = 0; k < 128; ++k) s += h0[k] * f1w[k * 64 + t];
        y1[t] = fmaxf(s, 0.f);
    }
    __syncthreads();
    if (t < 32) {
        float s = f2b[t];
        for (int k = 0; k < 64; ++k) s += y1[k] * f2w[k * 32 + t];
        y2[t] = fmaxf(s, 0.f);
    }
    __syncthreads();
    if (t == 0) {
        float s = f3b[0];
        for (int k = 0; k < 32; ++k) s += y2[k] * f3w[k];
        out[0] = s;
    }
}

extern "C" void kernel_launch(void* const* d_in, const int* in_sizes, int n_in,
                              void* d_out, int out_size, void* d_ws, size_t ws_size,
                              hipStream_t stream) {
    (void)in_sizes; (void)n_in; (void)out_size; (void)ws_size;
    const float* h        = (const float*)d_in[0];
    const int*   src      = (const int*)d_in[1];
    const int*   dst      = (const int*)d_in[2];
    const float* cw       = (const float*)d_in[3];
    const float* cb       = (const float*)d_in[4];
    const float* w_self1  = (const float*)d_in[5];
    const float* w_neigh1 = (const float*)d_in[6];
    const float* b1       = (const float*)d_in[7];
    const float* w_self2  = (const float*)d_in[8];
    const float* w_neigh2 = (const float*)d_in[9];
    const float* b2       = (const float*)d_in[10];
    const float* f1w      = (const float*)d_in[11];
    const float* f1b      = (const float*)d_in[12];
    const float* f2w      = (const float*)d_in[13];
    const float* f2b      = (const float*)d_in[14];
    const float* f3w      = (const float*)d_in[15];
    const float* f3b      = (const float*)d_in[16];
    float* out = (float*)d_out;

    // workspace layout (bytes); P overlays xa (xa dead after gemm1)
    char* ws = (char*)d_ws;
    float* xa    = (float*)(ws + 0);           // 50048*256*4 = 51,249,152
    float* P     = (float*)(ws + 0);           // overlay
    float* x2    = (float*)(ws + 51249152);    // 51,249,152
    float* wcat1 = (float*)(ws + 102498304);   // 262,144
    float* wcat2 = (float*)(ws + 102760448);   // 262,144
    int*   deg   = (int*)  (ws + 103022592);   // 200,192 (also cursor)
    int*   rowp  = (int*)  (ws + 103222784);   // 200,448
    int*   esrc  = (int*)  (ws + 103423232);   // 3,200,000
    float* hg    = (float*)(ws + 106623232);   // 512    (total ~106.6 MB)
    int*   cur   = deg;                        // alias: deg dead after scan

    hipMemsetAsync(deg, 0, N_NODES * sizeof(int), stream);
    hipMemsetAsync(hg, 0, 128 * sizeof(float), stream);

    padw1_kernel<<<256, 256, 0, stream>>>(w_self1, w_neigh1, wcat1);
    padw2_kernel<<<256, 256, 0, stream>>>(w_self2, w_neigh2, wcat2);
    deg_kernel<<<(N_EDGES + 255) / 256, 256, 0, stream>>>(dst, deg);
    scan_kernel<<<1, 1024, 0, stream>>>(deg, rowp, cur);
    fill_kernel<<<(N_EDGES + 255) / 256, 256, 0, stream>>>(src, dst, cur, esrc);
    conv_kernel<<<N_NODES, 128, 0, stream>>>(h, cw, cb, xa);
    agg_kernel<<<N_NODES, 128, 0, stream>>>(xa, rowp, esrc);
    dim3 g(MBLK, 2);
    gemm256<true><<<g, 256, 0, stream>>>(xa, wcat1, b1, x2);
    gemm256<false><<<g, 256, 0, stream>>>(x2, wcat2, nullptr, P);
    agg_epi_kernel<<<512, 128, 0, stream>>>(P, rowp, esrc, b2, hg);
    mlp_kernel<<<1, 128, 0, stream>>>(hg, f1w, f1b, f2w, f2b, f3w, f3b, out);
}

// Round 4
// 597.919 us; speedup vs baseline: 2.1624x; 1.6604x over previous
//
#include <hip/hip_runtime.h>

#define N_NODES 50000
#define N_EDGES 800000
#define IN_DIM  1024
#define COUT    127
#define H1      256
#define H2      128
#define LDA     256          // row stride (elements) of xa / x2 / P
#define MBLK    391          // ceil(50000/128)
#define NPART   4096         // agg_epi partial blocks
#define LDSS    72           // LDS row stride (elems) for MFMA tiles: 144 B -> 2-way only

typedef __bf16 bf16;
typedef __attribute__((ext_vector_type(8))) __bf16 bf16x8;
typedef __attribute__((ext_vector_type(4))) float floatx4;

// ---- conv1d: h[N,1024] -> xa[:, 0:128] bf16 (col 127 = 0), row stride 256 --
__global__ void conv_kernel(const float* __restrict__ h, const float* __restrict__ w,
                            const float* __restrict__ b, bf16* __restrict__ xa) {
    int n = blockIdx.x;
    int t = threadIdx.x;                           // 0..127
    const float* hr = h + (size_t)n * IN_DIM;
    float r = 0.f;
    if (t < COUT) {
        const float* p = hr + t * 8;               // 32B aligned
        float4 a = *(const float4*)p;
        float4 c = *(const float4*)(p + 4);
        float2 d = *(const float2*)(p + 8);
        float s = b[0];
        s += a.x * w[0] + a.y * w[1] + a.z * w[2] + a.w * w[3];
        s += c.x * w[4] + c.y * w[5] + c.z * w[6] + c.w * w[7];
        s += d.x * w[8] + d.y * w[9];
        r = fmaxf(s, 0.f);
    }
    xa[(size_t)n * LDA + t] = (bf16)r;
}

// ---------------- CSR build ----------------
__global__ void deg_kernel(const int* __restrict__ dst, int* __restrict__ deg) {
    int e = blockIdx.x * blockDim.x + threadIdx.x;
    if (e < N_EDGES) atomicAdd(&deg[dst[e]], 1);
}

__global__ __launch_bounds__(1024) void scan_kernel(const int* __restrict__ deg,
                                                    int* __restrict__ rowptr,
                                                    int* __restrict__ cursor) {
    __shared__ int wsum[16];
    __shared__ int carry_s;
    int tid = threadIdx.x;
    int lane = tid & 63, wid = tid >> 6;
    if (tid == 0) carry_s = 0;
    __syncthreads();
    for (int base = 0; base < N_NODES; base += 1024) {
        int i = base + tid;
        int v = (i < N_NODES) ? deg[i] : 0;
        int s = v;
        #pragma unroll
        for (int off = 1; off < 64; off <<= 1) {
            int t = __shfl_up(s, off);
            if (lane >= off) s += t;
        }
        if (lane == 63) wsum[wid] = s;
        __syncthreads();
        if (tid < 16) {
            int ws = wsum[tid];
            #pragma unroll
            for (int off = 1; off < 16; off <<= 1) {
                int t = __shfl_up(ws, off);
                if (tid >= off) ws += t;
            }
            wsum[tid] = ws;
        }
        __syncthreads();
        int wpre = (wid == 0) ? 0 : wsum[wid - 1];
        int excl = carry_s + wpre + (s - v);
        if (i < N_NODES) { rowptr[i] = excl; cursor[i] = excl; }
        int tot = wsum[15];
        __syncthreads();
        if (tid == 0) carry_s += tot;
        __syncthreads();
    }
    if (tid == 0) rowptr[N_NODES] = carry_s;
}

__global__ void fill_kernel(const int* __restrict__ src, const int* __restrict__ dst,
                            int* __restrict__ cursor, int* __restrict__ esrc) {
    int e = blockIdx.x * blockDim.x + threadIdx.x;
    if (e < N_EDGES) {
        int d = dst[e];
        int pos = atomicAdd(&cursor[d], 1);
        esrc[pos] = src[e];
    }
}

// ---- mean aggregation: xa[:, 128:256] = mean of in-neighbor xa[:, 0:128] ---
__global__ void agg_kernel(bf16* __restrict__ xa, const int* __restrict__ rowptr,
                           const int* __restrict__ esrc) {
    int n = blockIdx.x;
    int f = threadIdx.x;                           // 0..127
    int s0 = rowptr[n], s1 = rowptr[n + 1];
    float acc = 0.f;
    int e = s0;
    for (; e + 8 <= s1; e += 8) {
        int i0 = esrc[e],     i1 = esrc[e + 1], i2 = esrc[e + 2], i3 = esrc[e + 3];
        int i4 = esrc[e + 4], i5 = esrc[e + 5], i6 = esrc[e + 6], i7 = esrc[e + 7];
        float v0 = (float)xa[(size_t)i0 * LDA + f];
        float v1 = (float)xa[(size_t)i1 * LDA + f];
        float v2 = (float)xa[(size_t)i2 * LDA + f];
        float v3 = (float)xa[(size_t)i3 * LDA + f];
        float v4 = (float)xa[(size_t)i4 * LDA + f];
        float v5 = (float)xa[(size_t)i5 * LDA + f];
        float v6 = (float)xa[(size_t)i6 * LDA + f];
        float v7 = (float)xa[(size_t)i7 * LDA + f];
        acc += ((v0 + v1) + (v2 + v3)) + ((v4 + v5) + (v6 + v7));
    }
    for (; e < s1; ++e) acc += (float)xa[(size_t)esrc[e] * LDA + f];
    float dnm = (float)max(s1 - s0, 1);
    xa[(size_t)n * LDA + 128 + f] = (bf16)(acc / dnm);
}

// ---- WT1[n][k] bf16: transposed concat weights for layer 1 -----------------
// k<127: ws1[k][n]; k==127: 0; 128<=k<255: wn1[k-128][n]; k==255: 0
__global__ void padw1_kernel(const float* __restrict__ ws, const float* __restrict__ wn,
                             bf16* __restrict__ wt) {
    int i = blockIdx.x * blockDim.x + threadIdx.x; // 0 .. 65535
    int n = i >> 8, k = i & 255;
    float v = 0.f;
    if (k < COUT)                      v = ws[k * H1 + n];
    else if (k >= 128 && k < 128 + COUT) v = wn[(k - 128) * H1 + n];
    wt[i] = (bf16)v;
}

// ---- WT2[n][k] bf16: transposed concat weights for layer 2 -----------------
// n<128: ws2[k][n]; else wn2[k][n-128]
__global__ void padw2_kernel(const float* __restrict__ ws, const float* __restrict__ wn,
                             bf16* __restrict__ wt) {
    int i = blockIdx.x * blockDim.x + threadIdx.x; // 0 .. 65535
    int n = i >> 8, k = i & 255;
    float v = (n < H2) ? ws[k * H2 + n] : wn[k * H2 + (n - H2)];
    wt[i] = (bf16)v;
}

// ---- MFMA GEMM: out[N,256] = (relu?)(X[N,256] @ W[256,256] (+bias)), bf16 --
// WT is W transposed: WT[n][k]. Block: 256 thr = 4 waves; tile 128(M) x 64(N).
// Wave w: rows [32w,32w+32) as 2 m-tiles x 4 n-tiles of 16x16 MFMA C-tiles.
// Fragment layouts (guide-verified): A[m=lane&15][k=quad*8+j],
// B[k=quad*8+j][n=lane&15], D: col=lane&15, row=quad*4+reg.
template <bool RELU>
__global__ __launch_bounds__(256) void gemm_mfma(
        const bf16* __restrict__ X, const bf16* __restrict__ WT,
        const float* __restrict__ bias, bf16* __restrict__ out) {
    __shared__ bf16 As[128 * LDSS];                // 18432 B
    __shared__ bf16 Bs[64 * LDSS];                 //  9216 B
    int tid  = threadIdx.x;
    int lane = tid & 63, w = tid >> 6;
    int quad = lane >> 4, l16 = lane & 15;
    int m0 = blockIdx.x * 128;
    int n0 = blockIdx.y * 64;
    floatx4 acc[2][4] = {};

    for (int k0 = 0; k0 < 256; k0 += 64) {
        // stage A: 128 rows x 64 k (4 x 16B chunks/thread), B: 64 rows x 64 k
        uint4 av[4], bv[2];
        #pragma unroll
        for (int i = 0; i < 4; ++i) {
            int c = tid + 256 * i;                 // 0..1023
            int row = c >> 3, col = (c & 7) * 8;
            int gr = m0 + row;
            av[i] = (gr < N_NODES) ? *(const uint4*)(X + (size_t)gr * LDA + k0 + col)
                                   : make_uint4(0u, 0u, 0u, 0u);
        }
        #pragma unroll
        for (int i = 0; i < 2; ++i) {
            int c = tid + 256 * i;                 // 0..511
            int row = c >> 3, col = (c & 7) * 8;
            bv[i] = *(const uint4*)(WT + (size_t)(n0 + row) * 256 + k0 + col);
        }
        __syncthreads();                           // prior-slab reads done
        #pragma unroll
        for (int i = 0; i < 4; ++i) {
            int c = tid + 256 * i;
            int row = c >> 3, col = (c & 7) * 8;
            *(uint4*)&As[row * LDSS + col] = av[i];
        }
        #pragma unroll
        for (int i = 0; i < 2; ++i) {
            int c = tid + 256 * i;
            int row = c >> 3, col = (c & 7) * 8;
            *(uint4*)&Bs[row * LDSS + col] = bv[i];
        }
        __syncthreads();

        #pragma unroll
        for (int ks = 0; ks < 2; ++ks) {
            int kin = ks * 32 + quad * 8;
            bf16x8 a0 = *(const bf16x8*)&As[(w * 32 + l16) * LDSS + kin];
            bf16x8 a1 = *(const bf16x8*)&As[(w * 32 + 16 + l16) * LDSS + kin];
            bf16x8 b0 = *(const bf16x8*)&Bs[(l16) * LDSS + kin];
            bf16x8 b1 = *(const bf16x8*)&Bs[(16 + l16) * LDSS + kin];
            bf16x8 b2 = *(const bf16x8*)&Bs[(32 + l16) * LDSS + kin];
            bf16x8 b3 = *(const bf16x8*)&Bs[(48 + l16) * LDSS + kin];
            acc[0][0] = __builtin_amdgcn_mfma_f32_16x16x32_bf16(a0, b0, acc[0][0], 0, 0, 0);
            acc[0][1] = __builtin_amdgcn_mfma_f32_16x16x32_bf16(a0, b1, acc[0][1], 0, 0, 0);
            acc[0][2] = __builtin_amdgcn_mfma_f32_16x16x32_bf16(a0, b2, acc[0][2], 0, 0, 0);
            acc[0][3] = __builtin_amdgcn_mfma_f32_16x16x32_bf16(a0, b3, acc[0][3], 0, 0, 0);
            acc[1][0] = __builtin_amdgcn_mfma_f32_16x16x32_bf16(a1, b0, acc[1][0], 0, 0, 0);
            acc[1][1] = __builtin_amdgcn_mfma_f32_16x16x32_bf16(a1, b1, acc[1][1], 0, 0, 0);
            acc[1][2] = __builtin_amdgcn_mfma_f32_16x16x32_bf16(a1, b2, acc[1][2], 0, 0, 0);
            acc[1][3] = __builtin_amdgcn_mfma_f32_16x16x32_bf16(a1, b3, acc[1][3], 0, 0, 0);
        }
    }

    float bvv[4] = {};
    if constexpr (RELU) {
        #pragma unroll
        for (int nt = 0; nt < 4; ++nt) bvv[nt] = bias[n0 + nt * 16 + l16];
    }
    #pragma unroll
    for (int mt = 0; mt < 2; ++mt) {
        #pragma unroll
        for (int r = 0; r < 4; ++r) {
            int m = m0 + w * 32 + mt * 16 + quad * 4 + r;
            if (m < N_NODES) {
                #pragma unroll
                for (int nt = 0; nt < 4; ++nt) {
                    float v = acc[mt][nt][r];
                    if constexpr (RELU) v = fmaxf(v + bvv[nt], 0.f);
                    out[(size_t)m * LDA + n0 + nt * 16 + l16] = (bf16)v;
                }
            }
        }
    }
}

// ---- layer-2 aggregate + epilogue + partial pool ---------------------------
// P[:, :128] = x2@Ws2 (self), P[:, 128:] = x2@Wn2 (neigh projection).
// y2[n] = relu(P[n,:128] + mean_{src} P[src,128:] + b2); partial[blk] += y2.
__global__ __launch_bounds__(128) void agg_epi_kernel(
        const bf16* __restrict__ P, const int* __restrict__ rowptr,
        const int* __restrict__ esrc, const float* __restrict__ b2,
        float* __restrict__ partial) {
    int f = threadIdx.x;
    float bf = b2[f];
    float csum = 0.f;
    for (int n = blockIdx.x; n < N_NODES; n += gridDim.x) {
        int s0 = rowptr[n], s1 = rowptr[n + 1];
        float acc = 0.f;
        int e = s0;
        for (; e + 8 <= s1; e += 8) {
            int i0 = esrc[e],     i1 = esrc[e + 1], i2 = esrc[e + 2], i3 = esrc[e + 3];
            int i4 = esrc[e + 4], i5 = esrc[e + 5], i6 = esrc[e + 6], i7 = esrc[e + 7];
            float v0 = (float)P[(size_t)i0 * LDA + H2 + f];
            float v1 = (float)P[(size_t)i1 * LDA + H2 + f];
            float v2 = (float)P[(size_t)i2 * LDA + H2 + f];
            float v3 = (float)P[(size_t)i3 * LDA + H2 + f];
            float v4 = (float)P[(size_t)i4 * LDA + H2 + f];
            float v5 = (float)P[(size_t)i5 * LDA + H2 + f];
            float v6 = (float)P[(size_t)i6 * LDA + H2 + f];
            float v7 = (float)P[(size_t)i7 * LDA + H2 + f];
            acc += ((v0 + v1) + (v2 + v3)) + ((v4 + v5) + (v6 + v7));
        }
        for (; e < s1; ++e) acc += (float)P[(size_t)esrc[e] * LDA + H2 + f];
        float dnm = (float)max(s1 - s0, 1);
        float y = (float)P[(size_t)n * LDA + f] + acc / dnm + bf;
        csum += fmaxf(y, 0.f);
    }
    partial[(size_t)blockIdx.x * 128 + f] = csum;
}

// ---- reduce partials: hg[f] = sum_b partial[b][f] --------------------------
__global__ __launch_bounds__(256) void reduce_kernel(const float* __restrict__ partial,
                                                     float* __restrict__ hg) {
    int f = blockIdx.x, t = threadIdx.x;
    float s = 0.f;
    for (int i = t; i < NPART; i += 256) s += partial[(size_t)i * 128 + f];
    __shared__ float ls[4];
    #pragma unroll
    for (int off = 32; off >= 1; off >>= 1) s += __shfl_down(s, off);
    if ((t & 63) == 0) ls[t >> 6] = s;
    __syncthreads();
    if (t == 0) hg[f] = (ls[0] + ls[1]) + (ls[2] + ls[3]);
}

// ---------------- mean + MLP head (single block, fp32) ----------------------
__global__ void mlp_kernel(const float* __restrict__ hg,
                           const float* __restrict__ f1w, const float* __restrict__ f1b,
                           const float* __restrict__ f2w, const float* __restrict__ f2b,
                           const float* __restrict__ f3w, const float* __restrict__ f3b,
                           float* __restrict__ out) {
    __shared__ float h0[128], y1[64], y2[32];
    int t = threadIdx.x;
    if (t < 128) h0[t] = hg[t] * (1.0f / N_NODES);
    __syncthreads();
    if (t < 64) {
        float s = f1b[t];
        for (int k = 0; k < 128; ++k) s += h0[k] * f1w[k * 64 + t];
        y1[t] = fmaxf(s, 0.f);
    }
    __syncthreads();
    if (t < 32) {
        float s = f2b[t];
        for (int k = 0; k < 64; ++k) s += y1[k] * f2w[k * 32 + t];
        y2[t] = fmaxf(s, 0.f);
    }
    __syncthreads();
    if (t == 0) {
        float s = f3b[0];
        for (int k = 0; k < 32; ++k) s += y2[k] * f3w[k];
        out[0] = s;
    }
}

extern "C" void kernel_launch(void* const* d_in, const int* in_sizes, int n_in,
                              void* d_out, int out_size, void* d_ws, size_t ws_size,
                              hipStream_t stream) {
    (void)in_sizes; (void)n_in; (void)out_size; (void)ws_size;
    const float* h        = (const float*)d_in[0];
    const int*   src      = (const int*)d_in[1];
    const int*   dst      = (const int*)d_in[2];
    const float* cw       = (const float*)d_in[3];
    const float* cb       = (const float*)d_in[4];
    const float* w_self1  = (const float*)d_in[5];
    const float* w_neigh1 = (const float*)d_in[6];
    const float* b1       = (const float*)d_in[7];
    const float* w_self2  = (const float*)d_in[8];
    const float* w_neigh2 = (const float*)d_in[9];
    const float* b2       = (const float*)d_in[10];
    const float* f1w      = (const float*)d_in[11];
    const float* f1b      = (const float*)d_in[12];
    const float* f2w      = (const float*)d_in[13];
    const float* f2b      = (const float*)d_in[14];
    const float* f3w      = (const float*)d_in[15];
    const float* f3b      = (const float*)d_in[16];
    float* out = (float*)d_out;

    // workspace (bytes, 256-aligned); P overlays xa (xa dead after gemm1)
    char* ws = (char*)d_ws;
    bf16*  xa    = (bf16*) (ws + 0);           // 50048*256*2 = 25,624,576
    bf16*  P     = (bf16*) (ws + 0);           // overlay
    bf16*  x2    = (bf16*) (ws + 25624576);    // 25,624,576
    bf16*  wt1   = (bf16*) (ws + 51249152);    // 131,072
    bf16*  wt2   = (bf16*) (ws + 51380224);    // 131,072
    int*   deg   = (int*)  (ws + 51511296);    // 200,192 (also cursor)
    int*   rowp  = (int*)  (ws + 51711488);    // 200,448
    int*   esrc  = (int*)  (ws + 51911936);    // 3,200,000
    float* part  = (float*)(ws + 55111936);    // 4096*128*4 = 2,097,152
    float* hg    = (float*)(ws + 57209088);    // 512     (total ~57.2 MB)
    int*   cur   = deg;                        // alias: deg dead after scan

    hipMemsetAsync(deg, 0, N_NODES * sizeof(int), stream);

    padw1_kernel<<<256, 256, 0, stream>>>(w_self1, w_neigh1, wt1);
    padw2_kernel<<<256, 256, 0, stream>>>(w_self2, w_neigh2, wt2);
    deg_kernel<<<(N_EDGES + 255) / 256, 256, 0, stream>>>(dst, deg);
    scan_kernel<<<1, 1024, 0, stream>>>(deg, rowp, cur);
    fill_kernel<<<(N_EDGES + 255) / 256, 256, 0, stream>>>(src, dst, cur, esrc);
    conv_kernel<<<N_NODES, 128, 0, stream>>>(h, cw, cb, xa);
    agg_kernel<<<N_NODES, 128, 0, stream>>>(xa, rowp, esrc);
    dim3 g(MBLK, 4);
    gemm_mfma<true><<<g, 256, 0, stream>>>(xa, wt1, b1, x2);
    gemm_mfma<false><<<g, 256, 0, stream>>>(x2, wt2, nullptr, P);
    agg_epi_kernel<<<NPART, 128, 0, stream>>>(P, rowp, esrc, b2, part);
    reduce_kernel<<<128, 256, 0, stream>>>(part, hg);
    mlp_kernel<<<1, 128, 0, stream>>>(hg, f1w, f1b, f2w, f2b, f3w, f3b, out);
}